// Round 4
// baseline (826.139 us; speedup 1.0000x reference)
//
#include <hip/hip_runtime.h>
#include <hip/hip_bf16.h>

#define NN 50000
#define EE 800000
#define DD 128
#define NB 391     // ceil(50000/128) buckets of 128 nodes
#define EBLK 4096
#define NEB 196    // ceil(EE/4096)

typedef __attribute__((ext_vector_type(8))) short bf16x8;
typedef __attribute__((ext_vector_type(4))) float f32x4;

static __device__ __forceinline__ unsigned short f2bf(float f) {
  union { float f; unsigned u; } v; v.f = f;
  unsigned r = v.u + 0x7FFFu + ((v.u >> 16) & 1u);
  return (unsigned short)(r >> 16);
}
static __device__ __forceinline__ float bf2f(unsigned short h) {
  union { unsigned u; float f; } v; v.u = ((unsigned)h) << 16;
  return v.f;
}

// blocks [0,196): bucket histogram of dst>>7.
// blocks [196,228): Wt[n][k] bf16 combined (k<128: W_gcn, k>=128: W_lin).
// blocks [228,1796): x -> bf16 xb.
__global__ __launch_bounds__(256) void k_p0(
    const int* __restrict__ dst, int* __restrict__ bucketCnt,
    const float* __restrict__ Wg, const float* __restrict__ Wl,
    unsigned short* __restrict__ Wt, const float4* __restrict__ x4,
    ushort4* __restrict__ xb4) {
  int b = blockIdx.x, t = threadIdx.x;
  if (b < NEB) {
    __shared__ int cnt[NB];
    for (int i = t; i < NB; i += 256) cnt[i] = 0;
    __syncthreads();
    int e0 = b * EBLK;
    for (int i = t; i < EBLK; i += 256) {
      int e = e0 + i;
      if (e < EE) atomicAdd(&cnt[dst[e] >> 7], 1);
    }
    __syncthreads();
    for (int i = t; i < NB; i += 256)
      if (cnt[i]) atomicAdd(&bucketCnt[i], cnt[i]);
  } else if (b < NEB + 32) {
    for (int i = (b - NEB) * 256 + t; i < DD * 256; i += 32 * 256) {
      int n = i >> 8, k = i & 255;
      float v = (k < 128) ? Wg[k * DD + n] : Wl[(k - 128) * DD + n];
      Wt[i] = f2bf(v);
    }
  } else {
    int base = (b - NEB - 32) * 1024;
#pragma unroll
    for (int k = 0; k < 4; k++) {
      int i = base + t + k * 256;
      if (i < NN * 32) {
        float4 v = x4[i];
        ushort4 o;
        o.x = f2bf(v.x); o.y = f2bf(v.y); o.z = f2bf(v.z); o.w = f2bf(v.w);
        xb4[i] = o;
      }
    }
  }
}

__global__ __launch_bounds__(512) void k_pscan(const int* __restrict__ bucketCnt,
                                               int* __restrict__ bucketStart,
                                               int* __restrict__ cursor) {
  __shared__ int s[512];
  int t = threadIdx.x;
  int v = (t < NB) ? bucketCnt[t] : 0;
  s[t] = v;
  for (int off = 1; off < 512; off <<= 1) {
    __syncthreads();
    int tmp = (t >= off) ? s[t - off] : 0;
    __syncthreads();
    if (t >= off) s[t] += tmp;
  }
  __syncthreads();
  if (t < NB) {
    bucketStart[t] = s[t] - v;
    cursor[t] = s[t] - v;
  }
}

// Bin edges by bucket; packed record: src(16b) | dlocal(7b)<<16 | bucket(9b)<<23
__global__ __launch_bounds__(256) void k_p1(const int* __restrict__ src,
                                            const int* __restrict__ dst,
                                            int* __restrict__ cursor,
                                            unsigned int* __restrict__ pairs) {
  __shared__ unsigned int stage[EBLK];
  __shared__ int cnt[NB], base_[NB], cur[NB];
  int t = threadIdx.x;
  int e0 = blockIdx.x * EBLK;
  for (int i = t; i < NB; i += 256) { cnt[i] = 0; cur[i] = 0; }
  __syncthreads();
  for (int i = t; i < EBLK; i += 256) {
    int e = e0 + i;
    unsigned int p = 0xFFFFFFFFu;
    if (e < EE) {
      int d = dst[e], s = src[e];
      int bk = d >> 7;
      p = (unsigned int)s | ((unsigned int)(d & 127) << 16) | ((unsigned int)bk << 23);
      atomicAdd(&cnt[bk], 1);
    }
    stage[i] = p;
  }
  __syncthreads();
  for (int i = t; i < NB; i += 256)
    base_[i] = cnt[i] ? atomicAdd(&cursor[i], cnt[i]) : 0;
  __syncthreads();
  for (int i = t; i < EBLK; i += 256) {
    unsigned int p = stage[i];
    if (p != 0xFFFFFFFFu) {
      int bk = p >> 23;
      int ofs = atomicAdd(&cur[bk], 1);
      pairs[base_[bk] + ofs] = p;
    }
  }
}

// Per bucket: degree count -> dinv (global prerequisite for mega's src scaling)
__global__ __launch_bounds__(256) void k_pdeg(const unsigned int* __restrict__ pairs,
                                              const int* __restrict__ bucketStart,
                                              const int* __restrict__ bucketCnt,
                                              float* __restrict__ dinv) {
  __shared__ int ldeg[128];
  int b = blockIdx.x, t = threadIdx.x;
  if (t < 128) ldeg[t] = 0;
  __syncthreads();
  int start = bucketStart[b], cnt = bucketCnt[b];
  for (int i = t; i < cnt; i += 256)
    atomicAdd(&ldeg[(pairs[start + i] >> 16) & 127], 1);
  __syncthreads();
  int n0 = b << 7;
  if (t < 128 && n0 + t < NN)
    dinv[n0 + t] = rsqrtf((float)(ldeg[t] + 1));
}

// One block per 128-node bucket. 64KB LDS f32 accumulator, swizzled:
// (row,c) stored at row*128 + ((c + 4*row)&127)  [bank decorrelation].
// Phase 1: acc = self-loop; Phase 2: ds_add_f32 edge scatter;
// Phase 3: MFMA [agg*dinv | x] @ [Wg;Wl] + bias + LayerNorm -> out.
__global__ __launch_bounds__(512, 4) void k_mega(
    const unsigned int* __restrict__ pairs, const int* __restrict__ bucketStart,
    const int* __restrict__ bucketCnt, const unsigned short* __restrict__ xb,
    const float* __restrict__ dinv, const unsigned short* __restrict__ Wt,
    const float* __restrict__ bgcn, const float* __restrict__ lnw,
    const float* __restrict__ lnb, float* __restrict__ out) {
  __shared__ float acc[128 * 128];  // 64 KB exactly
  int b = blockIdx.x, t = threadIdx.x;
  int n0 = b << 7;
  // --- Phase 1: init with self-loop term dinv[row]*x[row] ---
  {
    int rr = t >> 2;
    int c0 = (t & 3) * 32;
    int row = n0 + rr; if (row > NN - 1) row = NN - 1;
    float di = dinv[row];
    const ushort4* xr = (const ushort4*)(xb + (size_t)row * DD + c0);
#pragma unroll
    for (int q = 0; q < 8; q++) {
      ushort4 u = xr[q];
      int c = c0 + q * 4;
      float4 wv;
      wv.x = bf2f(u.x) * di; wv.y = bf2f(u.y) * di;
      wv.z = bf2f(u.z) * di; wv.w = bf2f(u.w) * di;
      *(float4*)&acc[rr * 128 + ((c + 4 * rr) & 127)] = wv;
    }
  }
  __syncthreads();
  // --- Phase 2: edge scatter-aggregate (2 edges in flight per 16-lane group) ---
  {
    int start = bucketStart[b], cnt = bucketCnt[b];
    int g = t >> 4, r = t & 15;
    int i = g;
    unsigned int pA = (i < cnt) ? pairs[start + i] : 0;
    unsigned int pB = (i + 32 < cnt) ? pairs[start + i + 32] : 0;
    while (i < cnt) {
      int inext = i + 64;
      unsigned int nA = (inext < cnt) ? pairs[start + inext] : 0;
      unsigned int nB = (inext + 32 < cnt) ? pairs[start + inext + 32] : 0;
      int sA = pA & 0xFFFF, dA = (pA >> 16) & 127;
      int sB = pB & 0xFFFF, dB = (pB >> 16) & 127;
      bf16x8 vA = *(const bf16x8*)(xb + (size_t)sA * DD + r * 8);
      float diA = dinv[sA];
      bf16x8 vB = *(const bf16x8*)(xb + (size_t)sB * DD + r * 8);
      float diB = dinv[sB];
      int baseA = dA * 128, rotA = 8 * r + 4 * dA;
#pragma unroll
      for (int j = 0; j < 8; j++) {
        int jj = (j + r) & 7;
        atomicAdd(&acc[baseA + ((rotA + jj) & 127)],
                  bf2f((unsigned short)vA[jj]) * diA);
      }
      if (i + 32 < cnt) {
        int baseB = dB * 128, rotB = 8 * r + 4 * dB;
#pragma unroll
        for (int j = 0; j < 8; j++) {
          int jj = (j + r) & 7;
          atomicAdd(&acc[baseB + ((rotB + jj) & 127)],
                    bf2f((unsigned short)vB[jj]) * diB);
        }
      }
      i = inext; pA = nA; pB = nB;
    }
  }
  __syncthreads();
  // --- Phase 3: MFMA matmul + LayerNorm ---
  int w = t >> 6, lane = t & 63;
  int quad = lane >> 4, r = lane & 15;
  int mloc = w * 16 + r;  // A-row within block (0..127)
  int rowA = n0 + mloc; if (rowA > NN - 1) rowA = NN - 1;
  float diRow = dinv[rowA];
  f32x4 zero = {0.f, 0.f, 0.f, 0.f};
  f32x4 macc[8];
#pragma unroll
  for (int idx = 0; idx < 8; idx++) macc[idx] = zero;
#pragma unroll
  for (int ks = 0; ks < 8; ks++) {
    bf16x8 a;
    if (ks < 4) {
      int c = ks * 32 + quad * 8;
      float4 q0 = *(const float4*)&acc[mloc * 128 + ((c + 4 * mloc) & 127)];
      float4 q1 = *(const float4*)&acc[mloc * 128 + ((c + 4 + 4 * mloc) & 127)];
      a[0] = (short)f2bf(q0.x * diRow); a[1] = (short)f2bf(q0.y * diRow);
      a[2] = (short)f2bf(q0.z * diRow); a[3] = (short)f2bf(q0.w * diRow);
      a[4] = (short)f2bf(q1.x * diRow); a[5] = (short)f2bf(q1.y * diRow);
      a[6] = (short)f2bf(q1.z * diRow); a[7] = (short)f2bf(q1.w * diRow);
    } else {
      a = *(const bf16x8*)(xb + (size_t)rowA * DD + (ks - 4) * 32 + quad * 8);
    }
#pragma unroll
    for (int nt = 0; nt < 8; nt++) {
      bf16x8 bb = *(const bf16x8*)(Wt + (size_t)(nt * 16 + r) * 256 + ks * 32 + quad * 8);
      macc[nt] = __builtin_amdgcn_mfma_f32_16x16x32_bf16(a, bb, macc[nt], 0, 0, 0);
    }
  }
  float bg[8], lw[8], lb[8];
#pragma unroll
  for (int nt = 0; nt < 8; nt++) {
    int col = nt * 16 + r;
    bg[nt] = bgcn[col] + 1e-6f;
    lw[nt] = lnw[col];
    lb[nt] = lnb[col];
  }
#pragma unroll
  for (int reg = 0; reg < 4; reg++) {
    float y[8];
    float s1 = 0.f, s2 = 0.f;
#pragma unroll
    for (int nt = 0; nt < 8; nt++) {
      y[nt] = macc[nt][reg] + bg[nt];
      s1 += y[nt];
      s2 += y[nt] * y[nt];
    }
#pragma unroll
    for (int off = 1; off < 16; off <<= 1) {
      s1 += __shfl_xor(s1, off);
      s2 += __shfl_xor(s2, off);
    }
    float mu = s1 * (1.0f / 128.0f);
    float var = s2 * (1.0f / 128.0f) - mu * mu;
    float inv = rsqrtf(var + 1e-5f);
    int row = n0 + w * 16 + quad * 4 + reg;
    if (row < NN) {
#pragma unroll
      for (int nt = 0; nt < 8; nt++) {
        out[(size_t)row * DD + nt * 16 + r] = (y[nt] - mu) * inv * lw[nt] + lb[nt];
      }
    }
  }
}

extern "C" void kernel_launch(void* const* d_in, const int* in_sizes, int n_in,
                              void* d_out, int out_size, void* d_ws, size_t ws_size,
                              hipStream_t stream) {
  const int* adj = (const int*)d_in[0];
  const float* x = (const float*)d_in[1];
  const float* Wg = (const float*)d_in[2];
  const float* bg = (const float*)d_in[3];
  const float* Wl = (const float*)d_in[4];
  const float* lw = (const float*)d_in[5];
  const float* lb = (const float*)d_in[6];
  const int* srcp = adj;
  const int* dstp = adj + EE;
  float* out = (float*)d_out;

  char* ws = (char*)d_ws;
  size_t off = 0;
  auto alloc = [&](size_t bytes) -> void* {
    void* p = ws + off;
    off += (bytes + 255) & ~(size_t)255;
    return p;
  };
  int* bucketCnt = (int*)alloc(NB * 4);
  int* bucketStart = (int*)alloc(NB * 4);
  int* cursor = (int*)alloc(NB * 4);
  unsigned int* pairs = (unsigned int*)alloc((size_t)EE * 4);
  float* dinv = (float*)alloc((size_t)NN * 4);
  unsigned short* xb = (unsigned short*)alloc((size_t)NN * DD * 2);
  unsigned short* Wt = (unsigned short*)alloc((size_t)DD * 256 * 2);
  (void)ws_size; (void)in_sizes; (void)n_in; (void)out_size;

  hipMemsetAsync(bucketCnt, 0, NB * 4, stream);
  k_p0<<<NEB + 32 + 1568, 256, 0, stream>>>(dstp, bucketCnt, Wg, Wl, Wt,
                                            (const float4*)x, (ushort4*)xb);
  k_pscan<<<1, 512, 0, stream>>>(bucketCnt, bucketStart, cursor);
  k_p1<<<NEB, 256, 0, stream>>>(srcp, dstp, cursor, pairs);
  k_pdeg<<<NB, 256, 0, stream>>>(pairs, bucketStart, bucketCnt, dinv);
  k_mega<<<NB, 512, 0, stream>>>(pairs, bucketStart, bucketCnt, xb, dinv, Wt,
                                 bg, lw, lb, out);
}

// Round 5
// 194.435 us; speedup vs baseline: 4.2489x; 4.2489x over previous
//
#include <hip/hip_runtime.h>
#include <hip/hip_bf16.h>

#define NN 50000
#define EE 800000
#define DD 128
#define BKT 32
#define NB 1563     // ceil(NN/32)
#define EBLK 4096
#define NEB 196     // ceil(EE/4096)
#define CMAX 1024

typedef __attribute__((ext_vector_type(8))) short bf16x8;
typedef __attribute__((ext_vector_type(4))) float f32x4;

static __device__ __forceinline__ unsigned short f2bf(float f) {
  union { float f; unsigned u; } v; v.f = f;
  unsigned r = v.u + 0x7FFFu + ((v.u >> 16) & 1u);
  return (unsigned short)(r >> 16);
}
static __device__ __forceinline__ float bf2f(unsigned short h) {
  union { unsigned u; float f; } v; v.u = ((unsigned)h) << 16;
  return v.f;
}

// blocks [0,196): bucket histogram of dst>>5.
// blocks [196,228): Wt[n][k] bf16 combined (k<128: W_gcn, k>=128: W_lin).
// blocks [228,1791): x -> bf16 xb.
__global__ __launch_bounds__(256) void k_p0(
    const int* __restrict__ dst, int* __restrict__ bucketCnt,
    const float* __restrict__ Wg, const float* __restrict__ Wl,
    unsigned short* __restrict__ Wt, const float4* __restrict__ x4,
    ushort4* __restrict__ xb4) {
  int b = blockIdx.x, t = threadIdx.x;
  if (b < NEB) {
    __shared__ int cnt[NB];
    for (int i = t; i < NB; i += 256) cnt[i] = 0;
    __syncthreads();
    int e0 = b * EBLK;
    for (int i = t; i < EBLK; i += 256) {
      int e = e0 + i;
      if (e < EE) atomicAdd(&cnt[dst[e] >> 5], 1);
    }
    __syncthreads();
    for (int i = t; i < NB; i += 256)
      if (cnt[i]) atomicAdd(&bucketCnt[i], cnt[i]);
  } else if (b < NEB + 32) {
    for (int i = (b - NEB) * 256 + t; i < DD * 256; i += 32 * 256) {
      int n = i >> 8, k = i & 255;
      float v = (k < 128) ? Wg[k * DD + n] : Wl[(k - 128) * DD + n];
      Wt[i] = f2bf(v);
    }
  } else {
    int base = (b - NEB - 32) * 1024 + t;
#pragma unroll
    for (int k = 0; k < 4; k++) {
      int i = base + k * 256;
      if (i < NN * 32) {
        float4 v = x4[i];
        ushort4 o;
        o.x = f2bf(v.x); o.y = f2bf(v.y); o.z = f2bf(v.z); o.w = f2bf(v.w);
        xb4[i] = o;
      }
    }
  }
}

// 1 block: exclusive scan of 1563 bucket counts (4 items/thread).
__global__ __launch_bounds__(512) void k_pscan(const int* __restrict__ bucketCnt,
                                               int* __restrict__ bucketStart,
                                               int* __restrict__ cursor) {
  __shared__ int s[512];
  int t = threadIdx.x;
  int i0 = t * 4;
  int v0 = (i0 < NB) ? bucketCnt[i0] : 0;
  int v1 = (i0 + 1 < NB) ? bucketCnt[i0 + 1] : 0;
  int v2 = (i0 + 2 < NB) ? bucketCnt[i0 + 2] : 0;
  int v3 = (i0 + 3 < NB) ? bucketCnt[i0 + 3] : 0;
  int sum = v0 + v1 + v2 + v3;
  s[t] = sum;
  for (int off = 1; off < 512; off <<= 1) {
    __syncthreads();
    int tmp = (t >= off) ? s[t - off] : 0;
    __syncthreads();
    if (t >= off) s[t] += tmp;
  }
  __syncthreads();
  int pref = s[t] - sum;
  if (i0 < NB)     { bucketStart[i0] = pref;     cursor[i0] = pref; }
  pref += v0;
  if (i0 + 1 < NB) { bucketStart[i0 + 1] = pref; cursor[i0 + 1] = pref; }
  pref += v1;
  if (i0 + 2 < NB) { bucketStart[i0 + 2] = pref; cursor[i0 + 2] = pref; }
  pref += v2;
  if (i0 + 3 < NB) { bucketStart[i0 + 3] = pref; cursor[i0 + 3] = pref; }
}

// Bin edges by 32-node bucket. Record: src(16b) | dlocal(5b)<<16 | bucket(11b)<<21
__global__ __launch_bounds__(256) void k_p1(const int* __restrict__ src,
                                            const int* __restrict__ dst,
                                            int* __restrict__ cursor,
                                            unsigned int* __restrict__ pairs) {
  __shared__ unsigned int stage[EBLK];
  __shared__ int cnt[NB], base_[NB], cur[NB];
  int t = threadIdx.x;
  int e0 = blockIdx.x * EBLK;
  for (int i = t; i < NB; i += 256) { cnt[i] = 0; cur[i] = 0; }
  __syncthreads();
  for (int i = t; i < EBLK; i += 256) {
    int e = e0 + i;
    unsigned int p = 0xFFFFFFFFu;
    if (e < EE) {
      int d = dst[e], s = src[e];
      int bk = d >> 5;
      p = (unsigned int)s | ((unsigned int)(d & 31) << 16) | ((unsigned int)bk << 21);
      atomicAdd(&cnt[bk], 1);
    }
    stage[i] = p;
  }
  __syncthreads();
  for (int i = t; i < NB; i += 256)
    base_[i] = cnt[i] ? atomicAdd(&cursor[i], cnt[i]) : 0;
  __syncthreads();
  for (int i = t; i < EBLK; i += 256) {
    unsigned int p = stage[i];
    if (p != 0xFFFFFFFFu) {
      int bk = p >> 21;
      int ofs = atomicAdd(&cur[bk], 1);
      pairs[base_[bk] + ofs] = p;
    }
  }
}

// Per bucket: degree -> dinv (needed globally before mega2's gather).
__global__ __launch_bounds__(256) void k_pdeg(const unsigned int* __restrict__ pairs,
                                              const int* __restrict__ bucketStart,
                                              const int* __restrict__ bucketCnt,
                                              float* __restrict__ dinv) {
  __shared__ int ldeg[BKT];
  int b = blockIdx.x, t = threadIdx.x;
  if (t < BKT) ldeg[t] = 0;
  __syncthreads();
  int start = bucketStart[b], cnt = bucketCnt[b];
  for (int i = t; i < cnt; i += 256)
    atomicAdd(&ldeg[(pairs[start + i] >> 16) & 31], 1);
  __syncthreads();
  int n0 = b * BKT;
  if (t < BKT && n0 + t < NN)
    dinv[n0 + t] = rsqrtf((float)(ldeg[t] + 1));
}

// One block per 32-node bucket (~15 KB LDS -> 8 blocks/CU).
// Stage edges in LDS, build bucket-local CSR, register-accumulate gather
// (16 groups x 2 nodes, 2 rows in flight), then MFMA [agg|x]@[Wg;Wl] + LN.
__global__ __launch_bounds__(256) void k_mega2(
    const unsigned int* __restrict__ pairs, const int* __restrict__ bucketStart,
    const int* __restrict__ bucketCnt, const unsigned short* __restrict__ xb,
    const float* __restrict__ dinv, const unsigned short* __restrict__ Wt,
    const float* __restrict__ bgcn, const float* __restrict__ lnw,
    const float* __restrict__ lnb, float* __restrict__ out) {
  __shared__ unsigned int ep[CMAX];          // 4 KB
  __shared__ unsigned short csr[CMAX];       // 2 KB
  __shared__ int ldeg[BKT], lcur[BKT], rs_[BKT];
  __shared__ unsigned short abuf[BKT * 136]; // 8.5 KB, stride 136 (16B-aligned, 2-way banks)
  int b = blockIdx.x, t = threadIdx.x;
  int n0 = b * BKT;
  int g = t >> 4, r = t & 15;
  int start = bucketStart[b], cnt = bucketCnt[b];

  float acc0[8], acc1[8];
  {  // self-loop init: acc = dinv[node]*x[node]
    int nA = n0 + g;       int cA = (nA < NN) ? nA : (NN - 1);
    int nB = n0 + g + 16;  int cB = (nB < NN) ? nB : (NN - 1);
    float dA = dinv[cA], dB = dinv[cB];
    bf16x8 va = *(const bf16x8*)(xb + (size_t)cA * DD + r * 8);
    bf16x8 vb = *(const bf16x8*)(xb + (size_t)cB * DD + r * 8);
#pragma unroll
    for (int i = 0; i < 8; i++) acc0[i] = dA * bf2f((unsigned short)va[i]);
#pragma unroll
    for (int i = 0; i < 8; i++) acc1[i] = dB * bf2f((unsigned short)vb[i]);
  }

  for (int p = 0; p < cnt; p += CMAX) {
    int C = cnt - p; if (C > CMAX) C = CMAX;
    __syncthreads();               // protect ldeg/csr from previous chunk readers
    if (t < BKT) ldeg[t] = 0;
    __syncthreads();
    for (int i = t; i < C; i += 256) {
      unsigned int pr = pairs[start + p + i];
      ep[i] = pr;
      atomicAdd(&ldeg[(pr >> 16) & 31], 1);
    }
    __syncthreads();
    if (t < BKT) {                 // 32-wide exclusive scan via shfl_up (wave 0)
      int v = ldeg[t];
      int inc = v;
#pragma unroll
      for (int off = 1; off < BKT; off <<= 1) {
        int u = __shfl_up(inc, off);
        if (t >= off) inc += u;
      }
      rs_[t] = inc - v;
      lcur[t] = inc - v;
    }
    __syncthreads();
    for (int i = t; i < C; i += 256) {
      unsigned int pr = ep[i];
      int pos = atomicAdd(&lcur[(pr >> 16) & 31], 1);
      csr[pos] = (unsigned short)(pr & 0xFFFFu);
    }
    __syncthreads();
    {  // gather node n0+g into acc0 (2 rows in flight)
      int js = rs_[g], je = js + ldeg[g];
      int j = js;
      int s0 = (j < je) ? csr[j] : 0;
      int s1 = (j + 1 < je) ? csr[j + 1] : 0;
      while (j < je) {
        int jn = j + 2;
        int t0 = (jn < je) ? csr[jn] : 0;
        int t1 = (jn + 1 < je) ? csr[jn + 1] : 0;
        float d0 = dinv[s0];
        bf16x8 v0 = *(const bf16x8*)(xb + (size_t)s0 * DD + r * 8);
        float d1 = dinv[s1];
        bf16x8 v1 = *(const bf16x8*)(xb + (size_t)s1 * DD + r * 8);
#pragma unroll
        for (int i = 0; i < 8; i++) acc0[i] += d0 * bf2f((unsigned short)v0[i]);
        if (j + 1 < je) {
#pragma unroll
          for (int i = 0; i < 8; i++) acc0[i] += d1 * bf2f((unsigned short)v1[i]);
        }
        j = jn; s0 = t0; s1 = t1;
      }
    }
    {  // gather node n0+g+16 into acc1
      int gg = g + 16;
      int js = rs_[gg], je = js + ldeg[gg];
      int j = js;
      int s0 = (j < je) ? csr[j] : 0;
      int s1 = (j + 1 < je) ? csr[j + 1] : 0;
      while (j < je) {
        int jn = j + 2;
        int t0 = (jn < je) ? csr[jn] : 0;
        int t1 = (jn + 1 < je) ? csr[jn + 1] : 0;
        float d0 = dinv[s0];
        bf16x8 v0 = *(const bf16x8*)(xb + (size_t)s0 * DD + r * 8);
        float d1 = dinv[s1];
        bf16x8 v1 = *(const bf16x8*)(xb + (size_t)s1 * DD + r * 8);
#pragma unroll
        for (int i = 0; i < 8; i++) acc1[i] += d0 * bf2f((unsigned short)v0[i]);
        if (j + 1 < je) {
#pragma unroll
          for (int i = 0; i < 8; i++) acc1[i] += d1 * bf2f((unsigned short)v1[i]);
        }
        j = jn; s0 = t0; s1 = t1;
      }
    }
  }
  {  // finalize: scale by dinv[dst], bf16, stash in abuf
    int nA = n0 + g;       int cA = (nA < NN) ? nA : (NN - 1);
    int nB = n0 + g + 16;  int cB = (nB < NN) ? nB : (NN - 1);
    float dA = dinv[cA], dB = dinv[cB];
    bf16x8 oa, ob;
#pragma unroll
    for (int i = 0; i < 8; i++) oa[i] = (short)f2bf(acc0[i] * dA);
#pragma unroll
    for (int i = 0; i < 8; i++) ob[i] = (short)f2bf(acc1[i] * dB);
    *(bf16x8*)&abuf[g * 136 + r * 8] = oa;
    *(bf16x8*)&abuf[(g + 16) * 136 + r * 8] = ob;
  }
  __syncthreads();
  if (t < 128) {  // waves 0,1: 16-row MFMA tiles + fused LayerNorm
    int w = t >> 6, lane = t & 63;
    int quad = lane >> 4, rr = lane & 15;
    int mloc = w * 16 + rr;
    int rowA = n0 + mloc; int rc = (rowA < NN) ? rowA : (NN - 1);
    f32x4 zero = {0.f, 0.f, 0.f, 0.f};
    f32x4 macc[8];
#pragma unroll
    for (int i = 0; i < 8; i++) macc[i] = zero;
#pragma unroll
    for (int ks = 0; ks < 8; ks++) {
      bf16x8 a;
      if (ks < 4) a = *(const bf16x8*)&abuf[mloc * 136 + ks * 32 + quad * 8];
      else        a = *(const bf16x8*)(xb + (size_t)rc * DD + (ks - 4) * 32 + quad * 8);
#pragma unroll
      for (int nt = 0; nt < 8; nt++) {
        bf16x8 bb = *(const bf16x8*)(Wt + (size_t)(nt * 16 + rr) * 256 + ks * 32 + quad * 8);
        macc[nt] = __builtin_amdgcn_mfma_f32_16x16x32_bf16(a, bb, macc[nt], 0, 0, 0);
      }
    }
    float bg[8], lw[8], lb[8];
#pragma unroll
    for (int nt = 0; nt < 8; nt++) {
      int col = nt * 16 + rr;
      bg[nt] = bgcn[col] + 1e-6f;
      lw[nt] = lnw[col];
      lb[nt] = lnb[col];
    }
#pragma unroll
    for (int reg = 0; reg < 4; reg++) {
      float y[8];
      float s1 = 0.f, s2 = 0.f;
#pragma unroll
      for (int nt = 0; nt < 8; nt++) {
        y[nt] = macc[nt][reg] + bg[nt];
        s1 += y[nt];
        s2 += y[nt] * y[nt];
      }
#pragma unroll
      for (int off = 1; off < 16; off <<= 1) {
        s1 += __shfl_xor(s1, off);
        s2 += __shfl_xor(s2, off);
      }
      float mu = s1 * (1.0f / 128.0f);
      float var = s2 * (1.0f / 128.0f) - mu * mu;
      float inv = rsqrtf(var + 1e-5f);
      int row = n0 + w * 16 + quad * 4 + reg;
      if (row < NN) {
#pragma unroll
        for (int nt = 0; nt < 8; nt++) {
          out[(size_t)row * DD + nt * 16 + rr] = (y[nt] - mu) * inv * lw[nt] + lb[nt];
        }
      }
    }
  }
}

extern "C" void kernel_launch(void* const* d_in, const int* in_sizes, int n_in,
                              void* d_out, int out_size, void* d_ws, size_t ws_size,
                              hipStream_t stream) {
  const int* adj = (const int*)d_in[0];
  const float* x = (const float*)d_in[1];
  const float* Wg = (const float*)d_in[2];
  const float* bg = (const float*)d_in[3];
  const float* Wl = (const float*)d_in[4];
  const float* lw = (const float*)d_in[5];
  const float* lb = (const float*)d_in[6];
  const int* srcp = adj;
  const int* dstp = adj + EE;
  float* out = (float*)d_out;

  char* ws = (char*)d_ws;
  size_t off = 0;
  auto alloc = [&](size_t bytes) -> void* {
    void* p = ws + off;
    off += (bytes + 255) & ~(size_t)255;
    return p;
  };
  int* bucketCnt = (int*)alloc((size_t)NB * 4);
  int* bucketStart = (int*)alloc((size_t)NB * 4);
  int* cursor = (int*)alloc((size_t)NB * 4);
  unsigned int* pairs = (unsigned int*)alloc((size_t)EE * 4);
  float* dinv = (float*)alloc((size_t)NN * 4);
  unsigned short* xb = (unsigned short*)alloc((size_t)NN * DD * 2);
  unsigned short* Wt = (unsigned short*)alloc((size_t)DD * 256 * 2);
  (void)ws_size; (void)in_sizes; (void)n_in; (void)out_size;

  hipMemsetAsync(bucketCnt, 0, (size_t)NB * 4, stream);
  k_p0<<<NEB + 32 + 1563, 256, 0, stream>>>(dstp, bucketCnt, Wg, Wl, Wt,
                                            (const float4*)x, (ushort4*)xb);
  k_pscan<<<1, 512, 0, stream>>>(bucketCnt, bucketStart, cursor);
  k_p1<<<NEB, 256, 0, stream>>>(srcp, dstp, cursor, pairs);
  k_pdeg<<<NB, 256, 0, stream>>>(pairs, bucketStart, bucketCnt, dinv);
  k_mega2<<<NB, 256, 0, stream>>>(pairs, bucketStart, bucketCnt, xb, dinv, Wt,
                                  bg, lw, lb, out);
}

// Round 6
// 184.626 us; speedup vs baseline: 4.4747x; 1.0531x over previous
//
#include <hip/hip_runtime.h>
#include <hip/hip_bf16.h>

#define NN 50000
#define EE 800000
#define DD 128
#define CB 196      // coarse buckets of 256 nodes (196*256 = 50176)
#define NFB 1563    // fine buckets of 32 nodes (mega grid)
#define EBLK 2048
#define NEB 391     // ceil(EE/EBLK)

typedef __attribute__((ext_vector_type(8))) short bf16x8;
typedef __attribute__((ext_vector_type(4))) float f32x4;

static __device__ __forceinline__ unsigned short f2bf(float f) {
  union { float f; unsigned u; } v; v.f = f;
  unsigned r = v.u + 0x7FFFu + ((v.u >> 16) & 1u);
  return (unsigned short)(r >> 16);
}
static __device__ __forceinline__ float bf2f(unsigned short h) {
  union { unsigned u; float f; } v; v.u = ((unsigned)h) << 16;
  return v.f;
}

// blocks [0,391): coarse histogram of dst>>8.
// blocks [391,423): Wt[n][k] bf16 combined (k<128: W_gcn, k>=128: W_lin).
// blocks [423,1986): x -> bf16 xb (unscaled).
__global__ __launch_bounds__(256) void k_p0(
    const int* __restrict__ dst, int* __restrict__ coarseCnt,
    const float* __restrict__ Wg, const float* __restrict__ Wl,
    unsigned short* __restrict__ Wt, const float4* __restrict__ x4,
    ushort4* __restrict__ xb4) {
  int b = blockIdx.x, t = threadIdx.x;
  if (b < NEB) {
    __shared__ int cnt[CB];
    for (int i = t; i < CB; i += 256) cnt[i] = 0;
    __syncthreads();
    int e0 = b * EBLK;
    for (int i = t; i < EBLK; i += 256) {
      int e = e0 + i;
      if (e < EE) atomicAdd(&cnt[dst[e] >> 8], 1);
    }
    __syncthreads();
    for (int i = t; i < CB; i += 256)
      if (cnt[i]) atomicAdd(&coarseCnt[i], cnt[i]);
  } else if (b < NEB + 32) {
    for (int i = (b - NEB) * 256 + t; i < DD * 256; i += 32 * 256) {
      int n = i >> 8, k = i & 255;
      float v = (k < 128) ? Wg[k * DD + n] : Wl[(k - 128) * DD + n];
      Wt[i] = f2bf(v);
    }
  } else {
    int base = (b - NEB - 32) * 1024 + t;
#pragma unroll
    for (int k = 0; k < 4; k++) {
      int i = base + k * 256;
      if (i < NN * 32) {
        float4 v = x4[i];
        ushort4 o;
        o.x = f2bf(v.x); o.y = f2bf(v.y); o.z = f2bf(v.z); o.w = f2bf(v.w);
        xb4[i] = o;
      }
    }
  }
}

// 1 block: exclusive scan of 196 coarse counts.
__global__ __launch_bounds__(256) void k_pscan(const int* __restrict__ coarseCnt,
                                               int* __restrict__ coarseStart,
                                               int* __restrict__ cursor) {
  __shared__ int s[256];
  int t = threadIdx.x;
  int v = (t < CB) ? coarseCnt[t] : 0;
  s[t] = v;
  for (int off = 1; off < 256; off <<= 1) {
    __syncthreads();
    int tmp = (t >= off) ? s[t - off] : 0;
    __syncthreads();
    if (t >= off) s[t] += tmp;
  }
  __syncthreads();
  if (t < CB) {
    coarseStart[t] = s[t] - v;
    cursor[t] = s[t] - v;
  }
}

// Bin edges into coarse runs. Record: src(16b) | dlocal(8b)<<16 | coarse(8b)<<24
__global__ __launch_bounds__(256) void k_p1a(const int* __restrict__ src,
                                             const int* __restrict__ dst,
                                             int* __restrict__ cursor,
                                             unsigned int* __restrict__ pairs) {
  __shared__ unsigned int stage[EBLK];
  __shared__ int cnt[CB], base_[CB], cur[CB];
  int t = threadIdx.x;
  int e0 = blockIdx.x * EBLK;
  for (int i = t; i < CB; i += 256) { cnt[i] = 0; cur[i] = 0; }
  __syncthreads();
  for (int i = t; i < EBLK; i += 256) {
    int e = e0 + i;
    unsigned int p = 0xFFFFFFFFu;
    if (e < EE) {
      int d = dst[e], s = src[e];
      int cb = d >> 8;
      p = (unsigned int)s | ((unsigned int)(d & 255) << 16) | ((unsigned int)cb << 24);
      atomicAdd(&cnt[cb], 1);
    }
    stage[i] = p;
  }
  __syncthreads();
  for (int i = t; i < CB; i += 256)
    base_[i] = cnt[i] ? atomicAdd(&cursor[i], cnt[i]) : 0;
  __syncthreads();
  for (int i = t; i < EBLK; i += 256) {
    unsigned int p = stage[i];
    if (p != 0xFFFFFFFFu) {
      int cb = p >> 24;
      int ofs = atomicAdd(&cur[cb], 1);
      pairs[base_[cb] + ofs] = p;
    }
  }
}

// One block per coarse bucket: two-pass counting sort to exact per-node CSR
// (u16 srcList, contiguous writes), deg/dinv/rowStart, and xs = dinv*xb rows.
__global__ __launch_bounds__(512) void k_p1b(
    const unsigned int* __restrict__ pairs, const int* __restrict__ coarseStart,
    const int* __restrict__ coarseCnt, const unsigned short* __restrict__ xb,
    int* __restrict__ deg, float* __restrict__ dinv, int* __restrict__ rowStart,
    unsigned short* __restrict__ srcU16, unsigned short* __restrict__ xs) {
  __shared__ int ldeg[256], lscan[256], lcur[256];
  __shared__ float ldinvs[256];
  int cb = blockIdx.x, t = threadIdx.x;
  int start = coarseStart[cb], cnt = coarseCnt[cb];
  int n0 = cb << 8;
  int nloc = NN - n0; if (nloc > 256) nloc = 256;
  if (t < 256) ldeg[t] = 0;
  __syncthreads();
  for (int i = t; i < cnt; i += 512)
    atomicAdd(&ldeg[(pairs[start + i] >> 16) & 255], 1);
  __syncthreads();
  if (t < 256) lscan[t] = ldeg[t];
  for (int off = 1; off < 256; off <<= 1) {
    __syncthreads();
    int tmp = (t >= off && t < 256) ? lscan[t - off] : 0;
    __syncthreads();
    if (t >= off && t < 256) lscan[t] += tmp;
  }
  __syncthreads();
  if (t < 256) {
    int dg = ldeg[t];
    int rs = start + lscan[t] - dg;
    lcur[t] = rs;
    float di = rsqrtf((float)(dg + 1));
    ldinvs[t] = di;
    if (t < nloc) { deg[n0 + t] = dg; dinv[n0 + t] = di; rowStart[n0 + t] = rs; }
  }
  __syncthreads();
  for (int i = t; i < cnt; i += 512) {
    unsigned int pr = pairs[start + i];
    int pos = atomicAdd(&lcur[(pr >> 16) & 255], 1);
    srcU16[pos] = (unsigned short)(pr & 0xFFFFu);
  }
  // xs rows for local nodes (scaled by dinv)
  for (int i = t; i < nloc * 16; i += 512) {
    int rr = i >> 4, q = i & 15;
    bf16x8 v = *(const bf16x8*)(xb + (size_t)(n0 + rr) * DD + q * 8);
    float di = ldinvs[rr];
    bf16x8 o;
#pragma unroll
    for (int k = 0; k < 8; k++) o[k] = (short)f2bf(bf2f((unsigned short)v[k]) * di);
    *(bf16x8*)(xs + (size_t)(n0 + rr) * DD + q * 8) = o;
  }
}

// Gather a node's CSR range into acc[8] (lane slice r*8), 4 rows in flight.
static __device__ __forceinline__ void gather16(
    const unsigned short* __restrict__ xs, const unsigned short* __restrict__ srcU16,
    int js, int cnt, int r, int srcLaneBase, float* acc) {
  for (int base = 0; base < cnt; base += 16) {
    int idx = (base + r < cnt) ? (int)srcU16[js + base + r] : 0;
    int m = cnt - base; if (m > 16) m = 16;
    int j = 0;
    for (; j + 4 <= m; j += 4) {
      int s0 = __shfl(idx, srcLaneBase + j);
      int s1 = __shfl(idx, srcLaneBase + j + 1);
      int s2 = __shfl(idx, srcLaneBase + j + 2);
      int s3 = __shfl(idx, srcLaneBase + j + 3);
      bf16x8 v0 = *(const bf16x8*)(xs + (size_t)s0 * DD + r * 8);
      bf16x8 v1 = *(const bf16x8*)(xs + (size_t)s1 * DD + r * 8);
      bf16x8 v2 = *(const bf16x8*)(xs + (size_t)s2 * DD + r * 8);
      bf16x8 v3 = *(const bf16x8*)(xs + (size_t)s3 * DD + r * 8);
#pragma unroll
      for (int k = 0; k < 8; k++) acc[k] += bf2f((unsigned short)v0[k]);
#pragma unroll
      for (int k = 0; k < 8; k++) acc[k] += bf2f((unsigned short)v1[k]);
#pragma unroll
      for (int k = 0; k < 8; k++) acc[k] += bf2f((unsigned short)v2[k]);
#pragma unroll
      for (int k = 0; k < 8; k++) acc[k] += bf2f((unsigned short)v3[k]);
    }
    for (; j < m; j++) {
      int s = __shfl(idx, srcLaneBase + j);
      bf16x8 v = *(const bf16x8*)(xs + (size_t)s * DD + r * 8);
#pragma unroll
      for (int k = 0; k < 8; k++) acc[k] += bf2f((unsigned short)v[k]);
    }
  }
}

// One block per 32-node fine bucket. No staging phases: register gather from
// pre-sorted u16 CSR, then MFMA [agg|x]@[Wg;Wl] + bias + LayerNorm.
__global__ __launch_bounds__(256) void k_mega3(
    const unsigned short* __restrict__ xs, const unsigned short* __restrict__ xb,
    const int* __restrict__ rowStart, const int* __restrict__ deg,
    const unsigned short* __restrict__ srcU16, const float* __restrict__ dinv,
    const unsigned short* __restrict__ Wt, const float* __restrict__ bgcn,
    const float* __restrict__ lnw, const float* __restrict__ lnb,
    float* __restrict__ out) {
  __shared__ unsigned short abuf[32 * 136];  // 8.7 KB
  int b = blockIdx.x, t = threadIdx.x;
  int n0 = b * 32;
  int g = t >> 4, r = t & 15;
  int lane = t & 63;
  int srcLaneBase = lane & 48;
  int nA = n0 + g;           // always < NN (max 49999)
  int nB = n0 + g + 16;
  bool vB = (nB < NN);
  float acc0[8], acc1[8];
  {  // self-loop init from pre-scaled xs
    bf16x8 va = *(const bf16x8*)(xs + (size_t)nA * DD + r * 8);
#pragma unroll
    for (int k = 0; k < 8; k++) acc0[k] = bf2f((unsigned short)va[k]);
    if (vB) {
      bf16x8 vb = *(const bf16x8*)(xs + (size_t)nB * DD + r * 8);
#pragma unroll
      for (int k = 0; k < 8; k++) acc1[k] = bf2f((unsigned short)vb[k]);
    } else {
#pragma unroll
      for (int k = 0; k < 8; k++) acc1[k] = 0.f;
    }
  }
  gather16(xs, srcU16, rowStart[nA], deg[nA], r, srcLaneBase, acc0);
  if (vB) gather16(xs, srcU16, rowStart[nB], deg[nB], r, srcLaneBase, acc1);
  {
    float dA = dinv[nA];
    bf16x8 oa, ob;
#pragma unroll
    for (int k = 0; k < 8; k++) oa[k] = (short)f2bf(acc0[k] * dA);
    if (vB) {
      float dB = dinv[nB];
#pragma unroll
      for (int k = 0; k < 8; k++) ob[k] = (short)f2bf(acc1[k] * dB);
    } else {
#pragma unroll
      for (int k = 0; k < 8; k++) ob[k] = 0;
    }
    *(bf16x8*)&abuf[g * 136 + r * 8] = oa;
    *(bf16x8*)&abuf[(g + 16) * 136 + r * 8] = ob;
  }
  __syncthreads();
  if (t < 128) {  // waves 0,1: two 16-row MFMA tiles + fused LayerNorm
    int w = t >> 6, lane2 = t & 63;
    int quad = lane2 >> 4, rr = lane2 & 15;
    int mloc = w * 16 + rr;
    int rowA = n0 + mloc; int rc = (rowA < NN) ? rowA : (NN - 1);
    f32x4 zero = {0.f, 0.f, 0.f, 0.f};
    f32x4 macc[8];
#pragma unroll
    for (int i = 0; i < 8; i++) macc[i] = zero;
#pragma unroll
    for (int ks = 0; ks < 8; ks++) {
      bf16x8 a;
      if (ks < 4) a = *(const bf16x8*)&abuf[mloc * 136 + ks * 32 + quad * 8];
      else        a = *(const bf16x8*)(xb + (size_t)rc * DD + (ks - 4) * 32 + quad * 8);
#pragma unroll
      for (int nt = 0; nt < 8; nt++) {
        bf16x8 bb = *(const bf16x8*)(Wt + (size_t)(nt * 16 + rr) * 256 + ks * 32 + quad * 8);
        macc[nt] = __builtin_amdgcn_mfma_f32_16x16x32_bf16(a, bb, macc[nt], 0, 0, 0);
      }
    }
    float bg[8], lw[8], lb[8];
#pragma unroll
    for (int nt = 0; nt < 8; nt++) {
      int col = nt * 16 + rr;
      bg[nt] = bgcn[col] + 1e-6f;
      lw[nt] = lnw[col];
      lb[nt] = lnb[col];
    }
#pragma unroll
    for (int reg = 0; reg < 4; reg++) {
      float y[8];
      float s1 = 0.f, s2 = 0.f;
#pragma unroll
      for (int nt = 0; nt < 8; nt++) {
        y[nt] = macc[nt][reg] + bg[nt];
        s1 += y[nt];
        s2 += y[nt] * y[nt];
      }
#pragma unroll
      for (int off = 1; off < 16; off <<= 1) {
        s1 += __shfl_xor(s1, off);
        s2 += __shfl_xor(s2, off);
      }
      float mu = s1 * (1.0f / 128.0f);
      float var = s2 * (1.0f / 128.0f) - mu * mu;
      float inv = rsqrtf(var + 1e-5f);
      int row = n0 + w * 16 + quad * 4 + reg;
      if (row < NN) {
#pragma unroll
        for (int nt = 0; nt < 8; nt++) {
          out[(size_t)row * DD + nt * 16 + rr] = (y[nt] - mu) * inv * lw[nt] + lb[nt];
        }
      }
    }
  }
}

extern "C" void kernel_launch(void* const* d_in, const int* in_sizes, int n_in,
                              void* d_out, int out_size, void* d_ws, size_t ws_size,
                              hipStream_t stream) {
  const int* adj = (const int*)d_in[0];
  const float* x = (const float*)d_in[1];
  const float* Wg = (const float*)d_in[2];
  const float* bg = (const float*)d_in[3];
  const float* Wl = (const float*)d_in[4];
  const float* lw = (const float*)d_in[5];
  const float* lb = (const float*)d_in[6];
  const int* srcp = adj;
  const int* dstp = adj + EE;
  float* out = (float*)d_out;

  char* ws = (char*)d_ws;
  size_t off = 0;
  auto alloc = [&](size_t bytes) -> void* {
    void* p = ws + off;
    off += (bytes + 255) & ~(size_t)255;
    return p;
  };
  int* coarseCnt = (int*)alloc((size_t)CB * 4);
  int* coarseStart = (int*)alloc((size_t)CB * 4);
  int* cursor = (int*)alloc((size_t)CB * 4);
  unsigned int* pairs = (unsigned int*)alloc((size_t)EE * 4);
  unsigned short* srcU16 = (unsigned short*)alloc((size_t)EE * 2);
  int* deg = (int*)alloc((size_t)NN * 4);
  float* dinv = (float*)alloc((size_t)NN * 4);
  int* rowStart = (int*)alloc((size_t)NN * 4);
  unsigned short* xb = (unsigned short*)alloc((size_t)NN * DD * 2);
  unsigned short* xs = (unsigned short*)alloc((size_t)NN * DD * 2);
  unsigned short* Wt = (unsigned short*)alloc((size_t)DD * 256 * 2);
  (void)ws_size; (void)in_sizes; (void)n_in; (void)out_size;

  hipMemsetAsync(coarseCnt, 0, (size_t)CB * 4, stream);
  k_p0<<<NEB + 32 + 1563, 256, 0, stream>>>(dstp, coarseCnt, Wg, Wl, Wt,
                                            (const float4*)x, (ushort4*)xb);
  k_pscan<<<1, 256, 0, stream>>>(coarseCnt, coarseStart, cursor);
  k_p1a<<<NEB, 256, 0, stream>>>(srcp, dstp, cursor, pairs);
  k_p1b<<<CB, 512, 0, stream>>>(pairs, coarseStart, coarseCnt, xb, deg, dinv,
                                rowStart, srcU16, xs);
  k_mega3<<<NFB, 256, 0, stream>>>(xs, xb, rowStart, deg, srcU16, dinv, Wt,
                                   bg, lw, lb, out);
}